// Round 3
// baseline (264.966 us; speedup 1.0000x reference)
//
#include <hip/hip_runtime.h>
#include <math.h>

#define BATCH 4096
#define NPTS  2048
#define THREADS 256
#define CHUNK   1024              // points per LDS chunk
#define NCHUNK  (NPTS / CHUNK)    // 2
#define CH_F4   (CHUNK * 3 / 4)   // 768 float4 per tensor per chunk

// accumulate one point: h[c*3+d] += src_c * (m * tgt_d)
#define ACC(sx, sy, sz, tx, ty, tz, mm) do {                                   \
    float d0 = (mm) * (tx), d1 = (mm) * (ty), d2 = (mm) * (tz);                \
    h[0] = fmaf((sx), d0, h[0]); h[1] = fmaf((sx), d1, h[1]); h[2] = fmaf((sx), d2, h[2]); \
    h[3] = fmaf((sy), d0, h[3]); h[4] = fmaf((sy), d1, h[4]); h[5] = fmaf((sy), d2, h[5]); \
    h[6] = fmaf((sz), d0, h[6]); h[7] = fmaf((sz), d1, h[7]); h[8] = fmaf((sz), d2, h[8]); \
} while (0)

// Kernel 1: H[b] = src^T diag(mask) tgt -> d_ws (9 floats per batch).
// Global loads are 100% lane-contiguous (float4, lane i -> byte 16*i);
// the stride-48 per-point access happens from LDS, where the ds_read_b128
// pattern (lane t -> byte 48t) covers all 32 banks once per 8 lanes: conflict-free.
__global__ __launch_bounds__(THREADS)
void reduce_kernel(const float* __restrict__ src, const float* __restrict__ tgt,
                   const float* __restrict__ mask, float* __restrict__ Hout)
{
    __shared__ float4 s_lds[CH_F4];   // 12 KB
    __shared__ float4 t_lds[CH_F4];   // 12 KB
    __shared__ float  shred[THREADS / 64][9];

    const int b   = blockIdx.x;
    const int tid = threadIdx.x;
    const float4* s4 = (const float4*)(src  + (size_t)b * (NPTS * 3));
    const float4* t4 = (const float4*)(tgt  + (size_t)b * (NPTS * 3));
    const float4* m4 = (const float4*)(mask + (size_t)b * NPTS);

    float h[9] = {0.f, 0.f, 0.f, 0.f, 0.f, 0.f, 0.f, 0.f, 0.f};

#pragma unroll
    for (int c = 0; c < NCHUNK; ++c) {
        // --- coalesced stage: 6 dense 1KB wave-loads + 1 for mask ---
        const int base = c * CH_F4;
        float4 sv0 = s4[base + tid];
        float4 sv1 = s4[base + 256 + tid];
        float4 sv2 = s4[base + 512 + tid];
        float4 tv0 = t4[base + tid];
        float4 tv1 = t4[base + 256 + tid];
        float4 tv2 = t4[base + 512 + tid];
        float4 m   = m4[c * (CHUNK / 4) + tid];   // mask stays in registers

        s_lds[tid]       = sv0;
        s_lds[256 + tid] = sv1;
        s_lds[512 + tid] = sv2;
        t_lds[tid]       = tv0;
        t_lds[256 + tid] = tv1;
        t_lds[512 + tid] = tv2;
        __syncthreads();

        // --- compute: thread t handles points 4t..4t+3 of this chunk ---
        float4 sa = s_lds[3 * tid], sb = s_lds[3 * tid + 1], sc = s_lds[3 * tid + 2];
        float4 ta = t_lds[3 * tid], tb = t_lds[3 * tid + 1], tc = t_lds[3 * tid + 2];
        ACC(sa.x, sa.y, sa.z, ta.x, ta.y, ta.z, m.x);
        ACC(sa.w, sb.x, sb.y, ta.w, tb.x, tb.y, m.y);
        ACC(sb.z, sb.w, sc.x, tb.z, tb.w, tc.x, m.z);
        ACC(sc.y, sc.z, sc.w, tc.y, tc.z, tc.w, m.w);

        if (c + 1 < NCHUNK) __syncthreads();   // protect LDS before re-stage
    }

    // wave-64 butterfly reduction of the 9 accumulators
#pragma unroll
    for (int off = 32; off > 0; off >>= 1) {
#pragma unroll
        for (int i = 0; i < 9; ++i) h[i] += __shfl_down(h[i], off);
    }

    const int wid  = tid >> 6;
    const int lane = tid & 63;
    __syncthreads();               // ensure compute reads of LDS done before reuse
    if (lane == 0) {
#pragma unroll
        for (int i = 0; i < 9; ++i) shred[wid][i] = h[i];
    }
    __syncthreads();

    if (tid < 9) {
        Hout[(size_t)b * 9 + tid] =
            shred[0][tid] + shred[1][tid] + shred[2][tid] + shred[3][tid];
    }
}

// Kernel 2: one thread per batch — fp64 Jacobi eigensolve of H^T H + Kabsch
// rotation via cross-product-completed bases (det<0 reflection handled
// implicitly). 4096 independent solves run concurrently chip-wide.
__global__ __launch_bounds__(THREADS)
void solve_kernel(const float* __restrict__ Hin, float* __restrict__ out)
{
    const int b = blockIdx.x * THREADS + threadIdx.x;
    if (b >= BATCH) return;

    double H[3][3];
#pragma unroll
    for (int i = 0; i < 9; ++i)
        H[i / 3][i % 3] = (double)Hin[(size_t)b * 9 + i];

    double A[3][3];
#pragma unroll
    for (int i = 0; i < 3; ++i)
#pragma unroll
        for (int j = 0; j < 3; ++j)
            A[i][j] = H[0][i] * H[0][j] + H[1][i] * H[1][j] + H[2][i] * H[2][j];

    double V[3][3] = {{1, 0, 0}, {0, 1, 0}, {0, 0, 1}};

    const int pq[3][3] = {{0, 1, 2}, {0, 2, 1}, {1, 2, 0}};
    for (int sweep = 0; sweep < 6; ++sweep) {
        for (int r = 0; r < 3; ++r) {
            const int p = pq[r][0], q = pq[r][1], k = pq[r][2];
            double apq = A[p][q];
            if (fabs(apq) > 1e-300) {
                double theta = (A[q][q] - A[p][p]) / (2.0 * apq);
                double t = 1.0 / (fabs(theta) + sqrt(theta * theta + 1.0));
                if (theta < 0.0) t = -t;
                double c = 1.0 / sqrt(t * t + 1.0);
                double s = t * c;
                double app = A[p][p], aqq = A[q][q];
                A[p][p] = app - t * apq;
                A[q][q] = aqq + t * apq;
                A[p][q] = A[q][p] = 0.0;
                double akp = A[k][p], akq = A[k][q];
                A[k][p] = A[p][k] = c * akp - s * akq;
                A[k][q] = A[q][k] = s * akp + c * akq;
#pragma unroll
                for (int i = 0; i < 3; ++i) {
                    double vip = V[i][p], viq = V[i][q];
                    V[i][p] = c * vip - s * viq;
                    V[i][q] = s * vip + c * viq;
                }
            }
        }
    }

    int i0 = 0;
    if (A[1][1] > A[i0][i0]) i0 = 1;
    if (A[2][2] > A[i0][i0]) i0 = 2;
    const int ca = (i0 + 1) % 3, cb = (i0 + 2) % 3;
    const int i1 = (A[ca][ca] >= A[cb][cb]) ? ca : cb;

    double v0[3], v1[3];
#pragma unroll
    for (int i = 0; i < 3; ++i) { v0[i] = V[i][i0]; v1[i] = V[i][i1]; }

    double b0[3], b1[3];
#pragma unroll
    for (int r = 0; r < 3; ++r) {
        b0[r] = H[r][0] * v0[0] + H[r][1] * v0[1] + H[r][2] * v0[2];
        b1[r] = H[r][0] * v1[0] + H[r][1] * v1[1] + H[r][2] * v1[2];
    }
    double n0 = b0[0] * b0[0] + b0[1] * b0[1] + b0[2] * b0[2];
    double inv0 = 1.0 / sqrt(fmax(n0, 1e-300));
    double u0[3] = {b0[0] * inv0, b0[1] * inv0, b0[2] * inv0};
    double d01 = u0[0] * b1[0] + u0[1] * b1[1] + u0[2] * b1[2];
    double w[3] = {b1[0] - d01 * u0[0], b1[1] - d01 * u0[1], b1[2] - d01 * u0[2]};
    double nw = w[0] * w[0] + w[1] * w[1] + w[2] * w[2];
    double inv1 = 1.0 / sqrt(fmax(nw, 1e-300));
    double u1[3] = {w[0] * inv1, w[1] * inv1, w[2] * inv1};
    double u2[3] = {u0[1] * u1[2] - u0[2] * u1[1],
                    u0[2] * u1[0] - u0[0] * u1[2],
                    u0[0] * u1[1] - u0[1] * u1[0]};
    double v2[3] = {v0[1] * v1[2] - v0[2] * v1[1],
                    v0[2] * v1[0] - v0[0] * v1[2],
                    v0[0] * v1[1] - v0[1] * v1[0]};

    float* o = out + (size_t)b * 9;
#pragma unroll
    for (int r = 0; r < 3; ++r)
#pragma unroll
        for (int c = 0; c < 3; ++c)
            o[r * 3 + c] = (float)(v0[r] * u0[c] + v1[r] * u1[c] + v2[r] * u2[c]);
}

extern "C" void kernel_launch(void* const* d_in, const int* in_sizes, int n_in,
                              void* d_out, int out_size, void* d_ws, size_t ws_size,
                              hipStream_t stream) {
    const float* src  = (const float*)d_in[0];
    const float* tgt  = (const float*)d_in[1];
    // d_in[2] (kpt_src_mask) is unused by the reference
    const float* mask = (const float*)d_in[3];
    float* out = (float*)d_out;
    float* Hws = (float*)d_ws;   // 4096 * 9 floats = 147 KB scratch

    reduce_kernel<<<BATCH, THREADS, 0, stream>>>(src, tgt, mask, Hws);
    solve_kernel<<<(BATCH + THREADS - 1) / THREADS, THREADS, 0, stream>>>(Hws, out);
}

// Round 4
// 257.407 us; speedup vs baseline: 1.0294x; 1.0294x over previous
//
#include <hip/hip_runtime.h>
#include <math.h>

#define BATCH 4096
#define NPTS  2048
#define THREADS 256
#define PPB   1024                 // points per reduce-block
#define SUB   (NPTS / PPB)         // 2 partial blocks per batch
#define NBLK  (BATCH * SUB)        // 8192 reduce blocks

// accumulate one point: h[c*3+d] += src_c * (m * tgt_d)
#define ACC(sx, sy, sz, tx, ty, tz, mm) do {                                   \
    float d0 = (mm) * (tx), d1 = (mm) * (ty), d2 = (mm) * (tz);                \
    h[0] = fmaf((sx), d0, h[0]); h[1] = fmaf((sx), d1, h[1]); h[2] = fmaf((sx), d2, h[2]); \
    h[3] = fmaf((sy), d0, h[3]); h[4] = fmaf((sy), d1, h[4]); h[5] = fmaf((sy), d2, h[5]); \
    h[6] = fmaf((sz), d0, h[6]); h[7] = fmaf((sz), d1, h[7]); h[8] = fmaf((sz), d2, h[8]); \
} while (0)

// Kernel 1: partial H over a 1024-point slice. One group of 4 points per
// thread -> a single burst of 7 float4 loads, no inter-phase barriers, block
// retires right after one shuffle-reduce. 8192 blocks keep the memory
// request stream continuously deep (latency hiding via block-level TLP).
__global__ __launch_bounds__(THREADS, 8)
void reduce_kernel(const float* __restrict__ src, const float* __restrict__ tgt,
                   const float* __restrict__ mask, float* __restrict__ Hpart)
{
    const int blk  = blockIdx.x;          // 0..NBLK-1
    const int b    = blk / SUB;           // batch
    const int half = blk % SUB;           // slice within batch
    const int tid  = threadIdx.x;

    const float4* s4 = (const float4*)(src  + (size_t)b * (NPTS * 3) + (size_t)half * (PPB * 3));
    const float4* t4 = (const float4*)(tgt  + (size_t)b * (NPTS * 3) + (size_t)half * (PPB * 3));
    const float4* m4 = (const float4*)(mask + (size_t)b * NPTS       + (size_t)half * PPB);

    // one group of 4 points per thread: 3+3+1 float4 loads, all issued at once
    float4 m  = m4[tid];
    float4 sa = s4[3 * tid], sb = s4[3 * tid + 1], sc = s4[3 * tid + 2];
    float4 ta = t4[3 * tid], tb = t4[3 * tid + 1], tc = t4[3 * tid + 2];

    float h[9] = {0.f, 0.f, 0.f, 0.f, 0.f, 0.f, 0.f, 0.f, 0.f};
    ACC(sa.x, sa.y, sa.z, ta.x, ta.y, ta.z, m.x);
    ACC(sa.w, sb.x, sb.y, ta.w, tb.x, tb.y, m.y);
    ACC(sb.z, sb.w, sc.x, tb.z, tb.w, tc.x, m.z);
    ACC(sc.y, sc.z, sc.w, tc.y, tc.z, tc.w, m.w);

    // wave-64 butterfly reduction of the 9 accumulators
#pragma unroll
    for (int off = 32; off > 0; off >>= 1) {
#pragma unroll
        for (int i = 0; i < 9; ++i) h[i] += __shfl_down(h[i], off);
    }

    __shared__ float shred[THREADS / 64][9];
    const int wid  = tid >> 6;
    const int lane = tid & 63;
    if (lane == 0) {
#pragma unroll
        for (int i = 0; i < 9; ++i) shred[wid][i] = h[i];
    }
    __syncthreads();

    if (tid < 9) {
        Hpart[(size_t)blk * 9 + tid] =
            shred[0][tid] + shred[1][tid] + shred[2][tid] + shred[3][tid];
    }
}

// Kernel 2: one thread per batch — sum the SUB partials, then fp64 Jacobi
// eigensolve of H^T H + Kabsch rotation via cross-product-completed bases
// (det<0 reflection handled implicitly). 4096 solves run concurrently.
__global__ __launch_bounds__(THREADS)
void solve_kernel(const float* __restrict__ Hpart, float* __restrict__ out)
{
    const int b = blockIdx.x * THREADS + threadIdx.x;
    if (b >= BATCH) return;

    double H[3][3];
#pragma unroll
    for (int i = 0; i < 9; ++i) {
        double v = 0.0;
#pragma unroll
        for (int s = 0; s < SUB; ++s)
            v += (double)Hpart[((size_t)b * SUB + s) * 9 + i];
        H[i / 3][i % 3] = v;
    }

    double A[3][3];
#pragma unroll
    for (int i = 0; i < 3; ++i)
#pragma unroll
        for (int j = 0; j < 3; ++j)
            A[i][j] = H[0][i] * H[0][j] + H[1][i] * H[1][j] + H[2][i] * H[2][j];

    double V[3][3] = {{1, 0, 0}, {0, 1, 0}, {0, 0, 1}};

    const int pq[3][3] = {{0, 1, 2}, {0, 2, 1}, {1, 2, 0}};
    for (int sweep = 0; sweep < 6; ++sweep) {
        for (int r = 0; r < 3; ++r) {
            const int p = pq[r][0], q = pq[r][1], k = pq[r][2];
            double apq = A[p][q];
            if (fabs(apq) > 1e-300) {
                double theta = (A[q][q] - A[p][p]) / (2.0 * apq);
                double t = 1.0 / (fabs(theta) + sqrt(theta * theta + 1.0));
                if (theta < 0.0) t = -t;
                double c = 1.0 / sqrt(t * t + 1.0);
                double s = t * c;
                double app = A[p][p], aqq = A[q][q];
                A[p][p] = app - t * apq;
                A[q][q] = aqq + t * apq;
                A[p][q] = A[q][p] = 0.0;
                double akp = A[k][p], akq = A[k][q];
                A[k][p] = A[p][k] = c * akp - s * akq;
                A[k][q] = A[q][k] = s * akp + c * akq;
#pragma unroll
                for (int i = 0; i < 3; ++i) {
                    double vip = V[i][p], viq = V[i][q];
                    V[i][p] = c * vip - s * viq;
                    V[i][q] = s * vip + c * viq;
                }
            }
        }
    }

    int i0 = 0;
    if (A[1][1] > A[i0][i0]) i0 = 1;
    if (A[2][2] > A[i0][i0]) i0 = 2;
    const int ca = (i0 + 1) % 3, cb = (i0 + 2) % 3;
    const int i1 = (A[ca][ca] >= A[cb][cb]) ? ca : cb;

    double v0[3], v1[3];
#pragma unroll
    for (int i = 0; i < 3; ++i) { v0[i] = V[i][i0]; v1[i] = V[i][i1]; }

    double b0[3], b1[3];
#pragma unroll
    for (int r = 0; r < 3; ++r) {
        b0[r] = H[r][0] * v0[0] + H[r][1] * v0[1] + H[r][2] * v0[2];
        b1[r] = H[r][0] * v1[0] + H[r][1] * v1[1] + H[r][2] * v1[2];
    }
    double n0 = b0[0] * b0[0] + b0[1] * b0[1] + b0[2] * b0[2];
    double inv0 = 1.0 / sqrt(fmax(n0, 1e-300));
    double u0[3] = {b0[0] * inv0, b0[1] * inv0, b0[2] * inv0};
    double d01 = u0[0] * b1[0] + u0[1] * b1[1] + u0[2] * b1[2];
    double w[3] = {b1[0] - d01 * u0[0], b1[1] - d01 * u0[1], b1[2] - d01 * u0[2]};
    double nw = w[0] * w[0] + w[1] * w[1] + w[2] * w[2];
    double inv1 = 1.0 / sqrt(fmax(nw, 1e-300));
    double u1[3] = {w[0] * inv1, w[1] * inv1, w[2] * inv1};
    double u2[3] = {u0[1] * u1[2] - u0[2] * u1[1],
                    u0[2] * u1[0] - u0[0] * u1[2],
                    u0[0] * u1[1] - u0[1] * u1[0]};
    double v2[3] = {v0[1] * v1[2] - v0[2] * v1[1],
                    v0[2] * v1[0] - v0[0] * v1[2],
                    v0[0] * v1[1] - v0[1] * v1[0]};

    float* o = out + (size_t)b * 9;
#pragma unroll
    for (int r = 0; r < 3; ++r)
#pragma unroll
        for (int c = 0; c < 3; ++c)
            o[r * 3 + c] = (float)(v0[r] * u0[c] + v1[r] * u1[c] + v2[r] * u2[c]);
}

extern "C" void kernel_launch(void* const* d_in, const int* in_sizes, int n_in,
                              void* d_out, int out_size, void* d_ws, size_t ws_size,
                              hipStream_t stream) {
    const float* src  = (const float*)d_in[0];
    const float* tgt  = (const float*)d_in[1];
    // d_in[2] (kpt_src_mask) is unused by the reference
    const float* mask = (const float*)d_in[3];
    float* out = (float*)d_out;
    float* Hws = (float*)d_ws;   // NBLK * 9 floats = 295 KB scratch

    reduce_kernel<<<NBLK, THREADS, 0, stream>>>(src, tgt, mask, Hws);
    solve_kernel<<<(BATCH + THREADS - 1) / THREADS, THREADS, 0, stream>>>(Hws, out);
}

// Round 5
// 253.530 us; speedup vs baseline: 1.0451x; 1.0153x over previous
//
#include <hip/hip_runtime.h>
#include <math.h>

#define BATCH 4096
#define NPTS  2048
#define THREADS 256

typedef float f32x4 __attribute__((ext_vector_type(4)));

__device__ __forceinline__ f32x4 ntload(const f32x4* p) {
    return __builtin_nontemporal_load(p);
}

// accumulate one point: h[c*3+d] += src_c * (m * tgt_d)
#define ACC(sx, sy, sz, tx, ty, tz, mm) do {                                   \
    float d0 = (mm) * (tx), d1 = (mm) * (ty), d2 = (mm) * (tz);                \
    h[0] = fmaf((sx), d0, h[0]); h[1] = fmaf((sx), d1, h[1]); h[2] = fmaf((sx), d2, h[2]); \
    h[3] = fmaf((sy), d0, h[3]); h[4] = fmaf((sy), d1, h[4]); h[5] = fmaf((sy), d2, h[5]); \
    h[6] = fmaf((sz), d0, h[6]); h[7] = fmaf((sz), d1, h[7]); h[8] = fmaf((sz), d2, h[8]); \
} while (0)

// Kernel 1: H[b] = src^T diag(mask) tgt -> d_ws (9 floats per batch).
// One block per batch; each thread owns 2 groups of 4 points. All 14 float4
// loads are non-temporal (streamed-once data) and hoisted into one burst:
// 224 B in flight per thread, no barrier between them, single drain point.
__global__ __launch_bounds__(THREADS, 4)
void reduce_kernel(const float* __restrict__ src, const float* __restrict__ tgt,
                   const float* __restrict__ mask, float* __restrict__ Hout)
{
    const int b   = blockIdx.x;
    const int t   = threadIdx.x;           // group A: t, group B: t+256
    const f32x4* s4 = (const f32x4*)(src  + (size_t)b * (NPTS * 3));
    const f32x4* t4 = (const f32x4*)(tgt  + (size_t)b * (NPTS * 3));
    const f32x4* m4 = (const f32x4*)(mask + (size_t)b * NPTS);

    // ---- one burst: 14 independent NT loads ----
    f32x4 m0  = ntload(&m4[t]);
    f32x4 m1  = ntload(&m4[t + 256]);
    f32x4 sa0 = ntload(&s4[3 * t + 0]);
    f32x4 sb0 = ntload(&s4[3 * t + 1]);
    f32x4 sc0 = ntload(&s4[3 * t + 2]);
    f32x4 ta0 = ntload(&t4[3 * t + 0]);
    f32x4 tb0 = ntload(&t4[3 * t + 1]);
    f32x4 tc0 = ntload(&t4[3 * t + 2]);
    f32x4 sa1 = ntload(&s4[3 * (t + 256) + 0]);
    f32x4 sb1 = ntload(&s4[3 * (t + 256) + 1]);
    f32x4 sc1 = ntload(&s4[3 * (t + 256) + 2]);
    f32x4 ta1 = ntload(&t4[3 * (t + 256) + 0]);
    f32x4 tb1 = ntload(&t4[3 * (t + 256) + 1]);
    f32x4 tc1 = ntload(&t4[3 * (t + 256) + 2]);

    float h[9] = {0.f, 0.f, 0.f, 0.f, 0.f, 0.f, 0.f, 0.f, 0.f};
    ACC(sa0.x, sa0.y, sa0.z, ta0.x, ta0.y, ta0.z, m0.x);
    ACC(sa0.w, sb0.x, sb0.y, ta0.w, tb0.x, tb0.y, m0.y);
    ACC(sb0.z, sb0.w, sc0.x, tb0.z, tb0.w, tc0.x, m0.z);
    ACC(sc0.y, sc0.z, sc0.w, tc0.y, tc0.z, tc0.w, m0.w);
    ACC(sa1.x, sa1.y, sa1.z, ta1.x, ta1.y, ta1.z, m1.x);
    ACC(sa1.w, sb1.x, sb1.y, ta1.w, tb1.x, tb1.y, m1.y);
    ACC(sb1.z, sb1.w, sc1.x, tb1.z, tb1.w, tc1.x, m1.z);
    ACC(sc1.y, sc1.z, sc1.w, tc1.y, tc1.z, tc1.w, m1.w);

    // wave-64 butterfly reduction of the 9 accumulators
#pragma unroll
    for (int off = 32; off > 0; off >>= 1) {
#pragma unroll
        for (int i = 0; i < 9; ++i) h[i] += __shfl_down(h[i], off);
    }

    __shared__ float shred[THREADS / 64][9];
    const int wid  = t >> 6;
    const int lane = t & 63;
    if (lane == 0) {
#pragma unroll
        for (int i = 0; i < 9; ++i) shred[wid][i] = h[i];
    }
    __syncthreads();

    if (t < 9) {
        Hout[(size_t)b * 9 + t] =
            shred[0][t] + shred[1][t] + shred[2][t] + shred[3][t];
    }
}

// Kernel 2: one thread per batch — fp64 Jacobi eigensolve of H^T H + Kabsch
// rotation via cross-product-completed bases (det<0 reflection handled
// implicitly). 4096 independent solves run concurrently chip-wide.
__global__ __launch_bounds__(THREADS)
void solve_kernel(const float* __restrict__ Hin, float* __restrict__ out)
{
    const int b = blockIdx.x * THREADS + threadIdx.x;
    if (b >= BATCH) return;

    double H[3][3];
#pragma unroll
    for (int i = 0; i < 9; ++i)
        H[i / 3][i % 3] = (double)Hin[(size_t)b * 9 + i];

    double A[3][3];
#pragma unroll
    for (int i = 0; i < 3; ++i)
#pragma unroll
        for (int j = 0; j < 3; ++j)
            A[i][j] = H[0][i] * H[0][j] + H[1][i] * H[1][j] + H[2][i] * H[2][j];

    double V[3][3] = {{1, 0, 0}, {0, 1, 0}, {0, 0, 1}};

    const int pq[3][3] = {{0, 1, 2}, {0, 2, 1}, {1, 2, 0}};
    for (int sweep = 0; sweep < 6; ++sweep) {
        for (int r = 0; r < 3; ++r) {
            const int p = pq[r][0], q = pq[r][1], k = pq[r][2];
            double apq = A[p][q];
            if (fabs(apq) > 1e-300) {
                double theta = (A[q][q] - A[p][p]) / (2.0 * apq);
                double t = 1.0 / (fabs(theta) + sqrt(theta * theta + 1.0));
                if (theta < 0.0) t = -t;
                double c = 1.0 / sqrt(t * t + 1.0);
                double s = t * c;
                double app = A[p][p], aqq = A[q][q];
                A[p][p] = app - t * apq;
                A[q][q] = aqq + t * apq;
                A[p][q] = A[q][p] = 0.0;
                double akp = A[k][p], akq = A[k][q];
                A[k][p] = A[p][k] = c * akp - s * akq;
                A[k][q] = A[q][k] = s * akp + c * akq;
#pragma unroll
                for (int i = 0; i < 3; ++i) {
                    double vip = V[i][p], viq = V[i][q];
                    V[i][p] = c * vip - s * viq;
                    V[i][q] = s * vip + c * viq;
                }
            }
        }
    }

    int i0 = 0;
    if (A[1][1] > A[i0][i0]) i0 = 1;
    if (A[2][2] > A[i0][i0]) i0 = 2;
    const int ca = (i0 + 1) % 3, cb = (i0 + 2) % 3;
    const int i1 = (A[ca][ca] >= A[cb][cb]) ? ca : cb;

    double v0[3], v1[3];
#pragma unroll
    for (int i = 0; i < 3; ++i) { v0[i] = V[i][i0]; v1[i] = V[i][i1]; }

    double b0[3], b1[3];
#pragma unroll
    for (int r = 0; r < 3; ++r) {
        b0[r] = H[r][0] * v0[0] + H[r][1] * v0[1] + H[r][2] * v0[2];
        b1[r] = H[r][0] * v1[0] + H[r][1] * v1[1] + H[r][2] * v1[2];
    }
    double n0 = b0[0] * b0[0] + b0[1] * b0[1] + b0[2] * b0[2];
    double inv0 = 1.0 / sqrt(fmax(n0, 1e-300));
    double u0[3] = {b0[0] * inv0, b0[1] * inv0, b0[2] * inv0};
    double d01 = u0[0] * b1[0] + u0[1] * b1[1] + u0[2] * b1[2];
    double w[3] = {b1[0] - d01 * u0[0], b1[1] - d01 * u0[1], b1[2] - d01 * u0[2]};
    double nw = w[0] * w[0] + w[1] * w[1] + w[2] * w[2];
    double inv1 = 1.0 / sqrt(fmax(nw, 1e-300));
    double u1[3] = {w[0] * inv1, w[1] * inv1, w[2] * inv1};
    double u2[3] = {u0[1] * u1[2] - u0[2] * u1[1],
                    u0[2] * u1[0] - u0[0] * u1[2],
                    u0[0] * u1[1] - u0[1] * u1[0]};
    double v2[3] = {v0[1] * v1[2] - v0[2] * v1[1],
                    v0[2] * v1[0] - v0[0] * v1[2],
                    v0[0] * v1[1] - v0[1] * v1[0]};

    float* o = out + (size_t)b * 9;
#pragma unroll
    for (int r = 0; r < 3; ++r)
#pragma unroll
        for (int c = 0; c < 3; ++c)
            o[r * 3 + c] = (float)(v0[r] * u0[c] + v1[r] * u1[c] + v2[r] * u2[c]);
}

extern "C" void kernel_launch(void* const* d_in, const int* in_sizes, int n_in,
                              void* d_out, int out_size, void* d_ws, size_t ws_size,
                              hipStream_t stream) {
    const float* src  = (const float*)d_in[0];
    const float* tgt  = (const float*)d_in[1];
    // d_in[2] (kpt_src_mask) is unused by the reference
    const float* mask = (const float*)d_in[3];
    float* out = (float*)d_out;
    float* Hws = (float*)d_ws;   // BATCH * 9 floats = 147 KB scratch

    reduce_kernel<<<BATCH, THREADS, 0, stream>>>(src, tgt, mask, Hws);
    solve_kernel<<<(BATCH + THREADS - 1) / THREADS, THREADS, 0, stream>>>(Hws, out);
}